// Round 2
// baseline (258.281 us; speedup 1.0000x reference)
//
#include <hip/hip_runtime.h>
#include <hip/hip_bf16.h>

// Gram matrix: G = X @ X^T, X = [512, 65536] fp32, out = [512, 512] fp32.
// Round 12: r11 (async global_load_lds staging) left dur unchanged at 100us:
// MfmaUtil 8.2 / VALUBusy 11.7 / Occ 24.9 -- still latency-bound. Cause: the
// __syncthreads() after global_load_lds drains vmcnt(0) EVERY iteration, so
// the full L2 load latency sits on the critical path 32 times, with only
// 2.5 blocks/CU (grid-limited) of TLP to cover it. This is the documented
// m97-structure stall; the proven fix is T3+T4:
//   - LDS DOUBLE-BUFFER (As/Bs x2 = 64 KB): issue tile t+1's loads into
//     buf^1 BEFORE computing tile t, wait only counted vmcnt(4/8) (the loads
//     just issued) -> previous tile's loads complete, next tile's stay in
//     flight across the barrier. Latency hides under ds_read+cvt+MFMA.
//   - raw s_barrier + asm waitcnt (NOT __syncthreads -- that drains vmcnt(0)).
//     Rule 18/21 discipline: sched_barrier(0) + "memory" clobbers so ds_reads
//     can't hoist above the visibility barrier and reads drain (lgkmcnt(0))
//     before the reuse barrier.
// Everything else (decode, source-side XOR swizzle, fragment layout, atomic
// epilogue, mirror kernel) identical to r11.
// History: r1 fused 135us; r10 symmetric 100us; r11 async-stage 100us
// (FETCH 185->84 MB but latency-bound).

typedef short bf16x8 __attribute__((ext_vector_type(8)));   // 8 bf16 = 4 VGPRs
typedef float f32x4  __attribute__((ext_vector_type(4)));   // MFMA acc

#define HW    65536
#define CDIM  512

__device__ __forceinline__ short f2bf(float f) {
    __hip_bfloat16 h = __float2bfloat16(f);   // RNE
    short s;
    __builtin_memcpy(&s, &h, sizeof(short));
    return s;
}

__device__ __forceinline__ bf16x8 cvt8(float4 a, float4 b) {
    bf16x8 v;
    v[0] = f2bf(a.x); v[1] = f2bf(a.y); v[2] = f2bf(a.z); v[3] = f2bf(a.w);
    v[4] = f2bf(b.x); v[5] = f2bf(b.y); v[6] = f2bf(b.z); v[7] = f2bf(b.w);
    return v;
}

// async global->LDS, 16 bytes per lane (dest = wave-uniform base + lane*16)
__device__ __forceinline__ void gload16(const float* g, float* l) {
    __builtin_amdgcn_global_load_lds(
        (const __attribute__((address_space(1))) void*)g,
        (__attribute__((address_space(3))) void*)l,
        16, 0, 0);
}

__global__ __launch_bounds__(256, 2)
void gram_kernel(const float* __restrict__ X, float* __restrict__ out) {
    // decode: p<384 -> upper tile o=p>>6 ; p>=384 -> diag tile (p-384)>>6.
    // all chunks: KC = 1024 (chunk = p&63), 32 iters of BK=32.
    const int p = blockIdx.x;
    int ti, tj;
    if (p < 384) {
        const int o = p >> 6;
        const int TI[6] = {0, 0, 0, 1, 1, 2};
        const int TJ[6] = {1, 2, 3, 2, 3, 3};
        ti = TI[o]; tj = TJ[o];
    } else {
        ti = tj = (p - 384) >> 6;
    }
    const int kbase = (p & 63) << 10;
    const bool diag = (ti == tj);

    // fp32 panels, linear [128][32], DOUBLE-BUFFERED (64 KB total).
    __shared__ float As[2][4096];
    __shared__ float Bs[2][4096];

    const int t    = threadIdx.x;
    const int wave = t >> 6;
    const int lane = t & 63;
    const int wm   = wave & 1;          // 2x2 wave grid, each wave = 64x64
    const int wn   = wave >> 1;

    // --- staging: thread t covers row (t>>3)+32r, 16B slot (t&7), r=0..3 ---
    // LDS slot s holds global k-slot s ^ (row&7)  (pre-swizzled source).
    const int srow = t >> 3;                       // 0..31
    const int sswz = (t & 7) ^ (srow & 7);
    const float* ga = X + (size_t)(ti * 128 + srow) * HW + kbase + sswz * 4;
    const float* gb = X + (size_t)(tj * 128 + srow) * HW + kbase + sswz * 4;

    // --- fragment read offsets (float units), two swizzled 16B halves each ---
    const int fm = lane & 15;
    const int kg = lane >> 4;           // k-group: 8 contiguous k = slots 2kg,2kg+1
    int a_off0[4], a_off1[4], b_off0[4], b_off1[4];
#pragma unroll
    for (int i = 0; i < 4; ++i) {
        const int ra = wm * 64 + i * 16 + fm;
        a_off0[i] = ra * 32 + ((( 2 * kg    ) ^ (ra & 7)) << 2);
        a_off1[i] = ra * 32 + (((2 * kg + 1) ^ (ra & 7)) << 2);
        const int rb = wn * 64 + i * 16 + fm;
        b_off0[i] = rb * 32 + ((( 2 * kg    ) ^ (rb & 7)) << 2);
        b_off1[i] = rb * 32 + (((2 * kg + 1) ^ (rb & 7)) << 2);
    }

    f32x4 acc[4][4];
#pragma unroll
    for (int i = 0; i < 4; ++i)
#pragma unroll
        for (int j = 0; j < 4; ++j)
            acc[i][j] = (f32x4){0.f, 0.f, 0.f, 0.f};

    // issue one tile's staging loads into buffer `buf` (4 gloads, 8 if off-diag)
#define STAGE(buf, itn) do {                                                   \
        const float* g_ = ga + (itn) * 32;                                     \
        float* l_ = &As[buf][t * 4];                                           \
        _Pragma("unroll")                                                      \
        for (int r_ = 0; r_ < 4; ++r_)                                         \
            gload16(g_ + (size_t)r_ * 32 * HW, l_ + r_ * 1024);                \
        if (!diag) {                                                           \
            const float* g2_ = gb + (itn) * 32;                                \
            float* l2_ = &Bs[buf][t * 4];                                      \
            _Pragma("unroll")                                                  \
            for (int r_ = 0; r_ < 4; ++r_)                                     \
                gload16(g2_ + (size_t)r_ * 32 * HW, l2_ + r_ * 1024);          \
        }                                                                      \
    } while (0)

    STAGE(0, 0);                           // prologue: tile 0 in flight

    for (int it = 0; it < 32; ++it) {
        const int cur = it & 1;

        if (it < 31) {
            STAGE(cur ^ 1, it + 1);        // next tile's loads -> in flight
            // wait for CURRENT tile only: the loads just issued stay pending
            if (diag) asm volatile("s_waitcnt vmcnt(4)" ::: "memory");
            else      asm volatile("s_waitcnt vmcnt(8)" ::: "memory");
        } else {
            asm volatile("s_waitcnt vmcnt(0)" ::: "memory");
        }
        __builtin_amdgcn_s_barrier();      // all waves' stage of `cur` visible
        asm volatile("" ::: "memory");
        __builtin_amdgcn_sched_barrier(0); // ds_reads must not hoist above

        const float* Ab = As[cur];
        const float* Bb = diag ? As[cur] : Bs[cur];

        // LDS fp32 -> bf16 fragments (cvt at read; VALU has headroom)
        bf16x8 af[4], bfr[4];
#pragma unroll
        for (int i = 0; i < 4; ++i) {
            const float4 h0 = *(const float4*)(Ab + a_off0[i]);
            const float4 h1 = *(const float4*)(Ab + a_off1[i]);
            af[i] = cvt8(h0, h1);
        }
#pragma unroll
        for (int j = 0; j < 4; ++j) {
            const float4 h0 = *(const float4*)(Bb + b_off0[j]);
            const float4 h1 = *(const float4*)(Bb + b_off1[j]);
            bfr[j] = cvt8(h0, h1);
        }

#pragma unroll
        for (int i = 0; i < 4; ++i)
#pragma unroll
            for (int j = 0; j < 4; ++j)
                acc[i][j] = __builtin_amdgcn_mfma_f32_16x16x32_bf16(
                    af[i], bfr[j], acc[i][j], 0, 0, 0);

        // reuse barrier: all waves done READING `cur` before it+1 overwrites it
        __builtin_amdgcn_sched_barrier(0);
        asm volatile("s_waitcnt lgkmcnt(0)" ::: "memory");
        __builtin_amdgcn_s_barrier();
        asm volatile("" ::: "memory");
    }
#undef STAGE

    // --- epilogue: row-major coalesced atomics (diag/upper tiles only) ---
    // C/D layout (verified m89/m91): col = lane&15, row = (lane>>4)*4 + reg
    const int orow0 = ti * 128 + wm * 64 + (lane >> 4) * 4;
    const int ocol0 = tj * 128 + wn * 64 + fm;
#pragma unroll
    for (int i = 0; i < 4; ++i)
#pragma unroll
        for (int j = 0; j < 4; ++j)
#pragma unroll
            for (int r = 0; r < 4; ++r)
                atomicAdd(out + (orow0 + i * 16 + r) * CDIM + ocol0 + j * 16,
                          acc[i][j][r]);
}

// ---------------- mirror: copy upper tiles transposed into lower ----------------
__global__ __launch_bounds__(256)
void mirror_kernel(float* __restrict__ out) {
    const int id = blockIdx.x * 256 + threadIdx.x;   // 0..262143
    const int r = id >> 9;
    const int c = id & 511;
    if ((r >> 7) > (c >> 7))
        out[id] = out[c * CDIM + r];
}

extern "C" void kernel_launch(void* const* d_in, const int* in_sizes, int n_in,
                              void* d_out, int out_size, void* d_ws, size_t ws_size,
                              hipStream_t stream) {
    const float* x = (const float*)d_in[0];
    float* out = (float*)d_out;

    // zero the accumulator (harness poisons d_out with 0xAA before every launch)
    hipMemsetAsync(d_out, 0, (size_t)out_size * sizeof(float), stream);

    gram_kernel<<<dim3(640), dim3(256), 0, stream>>>(x, out);
    mirror_kernel<<<dim3(1024), dim3(256), 0, stream>>>(out);
}